// Round 1
// 225.174 us; speedup vs baseline: 1.1107x; 1.1107x over previous
//
#include <hip/hip_runtime.h>
#include <hip/hip_bf16.h>
#include <cstddef>
#include <cstdint>

#define B_  8
#define S_  32
#define BT_ 256      // B*S
#define N_  2000
#define E_  64000
#define GH_ 32
#define H_  64
#define G4_ 256      // 4*H
#define D_  64000    // N*GH
#define NEG_SLOPE_ 0.2f

#define KC_   125    // K-chunks
#define NPC_  16     // nodes per chunk (125*16 = 2000)

typedef __attribute__((ext_vector_type(8))) short short8;
typedef __attribute__((ext_vector_type(4))) float floatx4;
union U8 { uint32_t u[4]; short8 s; };

__device__ __forceinline__ float fsigmoid(float x) { return 1.0f / (1.0f + __expf(-x)); }
__device__ __forceinline__ float ftanh_(float x)   { return 1.0f - 2.0f / (__expf(2.0f * x) + 1.0f); }

// Truncation-split of two f32 into packed bf16-hi and bf16-lo words.
// hi word = [bf16(v1) : bf16(v0)], lo word = [bf16(v1-hi1) : bf16(v0-hi0)].
// v_perm_b32 packs the two high-halves in one instruction.
__device__ __forceinline__ void split2(float v0, float v1, uint32_t& hi, uint32_t& lo) {
  uint32_t b0 = __float_as_uint(v0), b1 = __float_as_uint(v1);
  hi = __builtin_amdgcn_perm(b1, b0, 0x07060302u);
  float l0 = v0 - __uint_as_float(b0 & 0xffff0000u);
  float l1 = v1 - __uint_as_float(b1 & 0xffff0000u);
  lo = __builtin_amdgcn_perm(__float_as_uint(l1), __float_as_uint(l0), 0x07060302u);
}

// ---------------------------------------------------------------------------
// GAT pipeline, CSR-gather formulation (unchanged this round).
// ---------------------------------------------------------------------------

// G1: degree histogram by dst
__global__ __launch_bounds__(256) void hist_kernel(
    const int* __restrict__ ei, int* __restrict__ deg)
{
  const int i = blockIdx.x * 256 + threadIdx.x;
  if (i < E_) atomicAdd(&deg[ei[E_ + i]], 1);
}

// G2: exclusive scan deg -> rowptr, copy to cursor. One block, 256 threads.
__global__ __launch_bounds__(256) void scan_kernel(
    const int* __restrict__ deg, int* __restrict__ rowptr, int* __restrict__ cursor)
{
  __shared__ int tsum[256];
  const int tid = threadIdx.x;
  int v[8];
  int s = 0;
  const int base = tid * 8;
#pragma unroll
  for (int j = 0; j < 8; ++j) {
    const int idx = base + j;
    const int d = (idx < N_) ? deg[idx] : 0;
    v[j] = s;            // local exclusive prefix
    s += d;
  }
  tsum[tid] = s;
  __syncthreads();
  // Hillis-Steele inclusive scan over 256 thread totals
  for (int off = 1; off < 256; off <<= 1) {
    int t = 0;
    if (tid >= off) t = tsum[tid - off];
    __syncthreads();
    tsum[tid] += t;
    __syncthreads();
  }
  const int ebase = tsum[tid] - s;  // exclusive base for this thread
#pragma unroll
  for (int j = 0; j < 8; ++j) {
    const int idx = base + j;
    if (idx < N_) {
      const int r = ebase + v[j];
      rowptr[idx] = r;
      cursor[idx] = r;
    }
  }
  if (tid == 0) rowptr[N_] = E_;
}

// G3: scatter src indices into CSR buckets
__global__ __launch_bounds__(256) void scatter_kernel(
    const int* __restrict__ ei, int* __restrict__ cursor, int* __restrict__ csr_src)
{
  const int i = blockIdx.x * 256 + threadIdx.x;
  if (i >= E_) return;
  const int s = ei[i];
  const int d = ei[E_ + i];
  const int pos = atomicAdd(&cursor[d], 1);
  csr_src[pos] = s;
}

// G4: transpose x [bt][n] -> xT [n][bt], 32x32 LDS tiles
__global__ __launch_bounds__(256) void transpose_kernel(
    const float* __restrict__ x, float* __restrict__ xT)
{
  __shared__ float tile[32][33];
  const int tx = threadIdx.x & 31;
  const int ty = threadIdx.x >> 5;  // 0..7
  const int n0  = blockIdx.x * 32;
  const int bt0 = blockIdx.y * 32;
#pragma unroll
  for (int r = 0; r < 4; ++r) {
    const int bt = bt0 + ty + r * 8;
    const int nn = n0 + tx;
    if (nn < N_) tile[ty + r * 8][tx] = x[(size_t)bt * N_ + nn];
  }
  __syncthreads();
#pragma unroll
  for (int r = 0; r < 4; ++r) {
    const int n = n0 + ty + r * 8;
    if (n < N_) xT[(size_t)n * BT_ + bt0 + tx] = tile[tx][ty + r * 8];
  }
}

// G5: gather-aggregate. One block per node n; thread = bt.
__global__ __launch_bounds__(256) void gat_gather_kernel(
    const float* __restrict__ xT, const int* __restrict__ rowptr,
    const int* __restrict__ csr_src,
    const float* __restrict__ w_lin, const float* __restrict__ att_src,
    const float* __restrict__ att_dst, float* __restrict__ agg_T)
{
  __shared__ int srcs[512];
  const int n   = blockIdx.x;
  const int tid = threadIdx.x;

  float c_s = 0.f, c_d = 0.f;
  for (int g = 0; g < GH_; ++g) {
    const float w = w_lin[g];
    c_s += w * att_src[g];
    c_d += w * att_dst[g];
  }

  const int r0 = rowptr[n];
  const int r1 = rowptr[n + 1];
  const int d  = r1 - r0;
  for (int i = tid; i < d && i < 512; i += 256) srcs[i] = csr_src[r0 + i];
  __syncthreads();

  const float xn = xT[(size_t)n * BT_ + tid];
  // self loop
  float e = (c_s + c_d) * xn;
  e = e > 0.f ? e : NEG_SLOPE_ * e;
  float w = __expf(e);
  float num = w * xn;
  float den = w;

  for (int p = 0; p < d; ++p) {
    int s;
    if (p < 512) s = srcs[p]; else s = csr_src[r0 + p];
    const float xs = xT[(size_t)s * BT_ + tid];
    float ee = c_s * xs + c_d * xn;
    ee = ee > 0.f ? ee : NEG_SLOPE_ * ee;
    const float ww = __expf(ee);
    num += ww * xs;
    den += ww;
  }
  agg_T[(size_t)n * BT_ + tid] = num / den;
}

// ---------------------------------------------------------------------------
// Kernel 2: split-bf16 MFMA matmul — RE-TILED (round 4).
// Old: wave owned 1 j-tile x 16 bt-tiles -> A-operand converted 16x overall
//      (4 waves x 4 nb blocks), VALUBusy 62% with MfmaUtil 14%.
// New: wave owns 4 bt-tiles x 4 j-tiles (square). A converted 4x (nb blocks),
//      B converted 4x (waves, loads L1-served). 32 split2-units per wave-nn
//      vs 68 before; MFMA count and summation order IDENTICAL.
// ---------------------------------------------------------------------------
__global__ __launch_bounds__(256) void gate_mfma_kernel(
    const float* __restrict__ W_ih, const float* __restrict__ agg_T,
    const float* __restrict__ w_lin, const float* __restrict__ gat_bias,
    float* __restrict__ partial, float* __restrict__ pre_gates, int use_atomic)
{
  __shared__ float agg_s[NPC_ * 256];

  const int tid  = threadIdx.x;
  const int nb   = blockIdx.x;      // j-block of 64 (4 j-tiles)
  const int kc   = blockIdx.y;      // K-chunk
  const int n0   = kc * NPC_;
  const int wv   = tid >> 6;        // wave owns bt in [wv*64, wv*64+64)
  const int lane = tid & 63;
  const int i16  = lane & 15;
  const int q    = lane >> 4;
  const int j0   = nb * 64;

  // stage agg chunk to LDS (16 nodes x 256 bt)
  {
    const float4* src = (const float4*)(agg_T + (size_t)n0 * 256);
    float4* dst = (float4*)agg_s;
#pragma unroll
    for (int p = 0; p < 4; ++p) dst[tid + p * 256] = src[tid + p * 256];
  }

  float wlr[8], gbr[8];
#pragma unroll
  for (int jx = 0; jx < 8; ++jx) {
    wlr[jx] = w_lin[q * 8 + jx];
    gbr[jx] = gat_bias[q * 8 + jx];
  }

  floatx4 acc[4][4];
#pragma unroll
  for (int mt = 0; mt < 4; ++mt)
#pragma unroll
    for (int jt = 0; jt < 4; ++jt)
#pragma unroll
      for (int r = 0; r < 4; ++r) acc[mt][jt][r] = 0.f;

  __syncthreads();

  // B row pointers, one per j-tile. Row j = j0 + jt*16 + i16; k base = n0*32 + q*8.
  const float* Wr0 = W_ih + (size_t)(j0 +  0 + i16) * D_ + (size_t)n0 * GH_ + q * 8;
  const float* Wr1 = W_ih + (size_t)(j0 + 16 + i16) * D_ + (size_t)n0 * GH_ + q * 8;
  const float* Wr2 = W_ih + (size_t)(j0 + 32 + i16) * D_ + (size_t)n0 * GH_ + q * 8;
  const float* Wr3 = W_ih + (size_t)(j0 + 48 + i16) * D_ + (size_t)n0 * GH_ + q * 8;

#pragma unroll 1
  for (int nn = 0; nn < NPC_; ++nn) {
    // ---- issue all B loads for this k-slice (8 x dwordx4) ----
    float4 b0[4], b1[4];
    b0[0] = *(const float4*)(Wr0 + nn * GH_);     b1[0] = *(const float4*)(Wr0 + nn * GH_ + 4);
    b0[1] = *(const float4*)(Wr1 + nn * GH_);     b1[1] = *(const float4*)(Wr1 + nn * GH_ + 4);
    b0[2] = *(const float4*)(Wr2 + nn * GH_);     b1[2] = *(const float4*)(Wr2 + nn * GH_ + 4);
    b0[3] = *(const float4*)(Wr3 + nn * GH_);     b1[3] = *(const float4*)(Wr3 + nn * GH_ + 4);

    // ---- A fragments for this wave's 4 bt-tiles (hides B load latency) ----
    short8 ah[4], al[4];
#pragma unroll
    for (int mt = 0; mt < 4; ++mt) {
      const float a = agg_s[nn * 256 + wv * 64 + mt * 16 + i16];
      U8 Hh, Ll;
#pragma unroll
      for (int p = 0; p < 4; ++p) {
        float v0 = fmaf(a, wlr[2 * p],     gbr[2 * p]);
        float v1 = fmaf(a, wlr[2 * p + 1], gbr[2 * p + 1]);
        v0 = fmaxf(v0, 0.f);
        v1 = fmaxf(v1, 0.f);
        split2(v0, v1, Hh.u[p], Ll.u[p]);
      }
      ah[mt] = Hh.s; al[mt] = Ll.s;
    }

    // ---- per j-tile: convert B once, feed 12 MFMAs ----
#pragma unroll
    for (int jt = 0; jt < 4; ++jt) {
      short8 bh, bl;
      {
        U8 Hh, Ll;
        split2(b0[jt].x, b0[jt].y, Hh.u[0], Ll.u[0]);
        split2(b0[jt].z, b0[jt].w, Hh.u[1], Ll.u[1]);
        split2(b1[jt].x, b1[jt].y, Hh.u[2], Ll.u[2]);
        split2(b1[jt].z, b1[jt].w, Hh.u[3], Ll.u[3]);
        bh = Hh.s; bl = Ll.s;
      }
#pragma unroll
      for (int mt = 0; mt < 4; ++mt) {
        acc[mt][jt] = __builtin_amdgcn_mfma_f32_16x16x32_bf16(ah[mt], bh, acc[mt][jt], 0, 0, 0);
        acc[mt][jt] = __builtin_amdgcn_mfma_f32_16x16x32_bf16(al[mt], bh, acc[mt][jt], 0, 0, 0);
        acc[mt][jt] = __builtin_amdgcn_mfma_f32_16x16x32_bf16(ah[mt], bl, acc[mt][jt], 0, 0, 0);
      }
    }
  }

  // ---- epilogue ----
#pragma unroll
  for (int mt = 0; mt < 4; ++mt) {
    const int bt = wv * 64 + mt * 16 + q * 4;
#pragma unroll
    for (int jt = 0; jt < 4; ++jt) {
      const int j = j0 + jt * 16 + i16;
      if (use_atomic) {
#pragma unroll
        for (int r = 0; r < 4; ++r) atomicAdd(&pre_gates[(bt + r) * G4_ + j], acc[mt][jt][r]);
      } else {
#pragma unroll
        for (int r = 0; r < 4; ++r)
          partial[((size_t)kc * 256 + (bt + r)) * 256 + j] = acc[mt][jt][r];
      }
    }
  }
}

// ---------------------------------------------------------------------------
// Kernel 2b: reduce partials -> pre_gates.
// ---------------------------------------------------------------------------
__global__ __launch_bounds__(256) void reduce_kernel(
    const float* __restrict__ partial, float* __restrict__ pre_gates)
{
  const int o = blockIdx.x * 256 + threadIdx.x;
  float s0 = 0.f, s1 = 0.f, s2 = 0.f, s3 = 0.f;
  int kc = 0;
  for (; kc + 4 <= KC_; kc += 4) {
    s0 += partial[(size_t)(kc + 0) * 65536 + o];
    s1 += partial[(size_t)(kc + 1) * 65536 + o];
    s2 += partial[(size_t)(kc + 2) * 65536 + o];
    s3 += partial[(size_t)(kc + 3) * 65536 + o];
  }
  for (; kc < KC_; ++kc) s0 += partial[(size_t)kc * 65536 + o];
  pre_gates[o] = (s0 + s1) + (s2 + s3);
}

// ---------------------------------------------------------------------------
// Kernel 3: LSTM recurrence. One block per batch b.
// ---------------------------------------------------------------------------
__global__ __launch_bounds__(256) void lstm_kernel(
    const float* __restrict__ pre_gates, const float* __restrict__ W_hh,
    const float* __restrict__ b_ih, const float* __restrict__ b_hh,
    float* __restrict__ hT)
{
  const int b   = blockIdx.x;
  const int tid = threadIdx.x;
  __shared__ float h_s[H_];
  __shared__ float g_s[G4_];

  float wr[H_];
#pragma unroll
  for (int k = 0; k < H_; ++k) wr[k] = W_hh[(size_t)tid * H_ + k];

  float pg[S_];
#pragma unroll
  for (int t = 0; t < S_; ++t) pg[t] = pre_gates[(size_t)(b * S_ + t) * G4_ + tid];

  const float bias = b_ih[tid] + b_hh[tid];
  if (tid < H_) h_s[tid] = 0.f;
  float c = 0.f;
  __syncthreads();

  for (int t = 0; t < S_; ++t) {
    float g0 = pg[t] + bias, g1 = 0.f, g2 = 0.f, g3 = 0.f;
#pragma unroll
    for (int k = 0; k < H_; k += 4) {
      g0 = fmaf(wr[k + 0], h_s[k + 0], g0);
      g1 = fmaf(wr[k + 1], h_s[k + 1], g1);
      g2 = fmaf(wr[k + 2], h_s[k + 2], g2);
      g3 = fmaf(wr[k + 3], h_s[k + 3], g3);
    }
    g_s[tid] = (g0 + g1) + (g2 + g3);
    __syncthreads();
    if (tid < H_) {
      const float ig = fsigmoid(g_s[tid]);
      const float fg = fsigmoid(g_s[H_ + tid]);
      const float gg = ftanh_(g_s[2 * H_ + tid]);
      const float og = fsigmoid(g_s[3 * H_ + tid]);
      c = fg * c + ig * gg;
      h_s[tid] = og * ftanh_(c);
    }
    __syncthreads();
  }
  if (tid < H_) hT[b * H_ + tid] = h_s[tid];
}

// ---------------------------------------------------------------------------
// Kernel 4: head.
// ---------------------------------------------------------------------------
__global__ __launch_bounds__(256) void head_kernel(
    const float* __restrict__ hT, const float* __restrict__ W_head,
    const float* __restrict__ b_head, float* __restrict__ out)
{
  const int o = blockIdx.x * 256 + threadIdx.x;
  if (o >= B_ * N_) return;
  const int b = o / N_;
  const int n = o - b * N_;
  const float4* w4 = (const float4*)(W_head + (size_t)n * H_);
  const float4* h4 = (const float4*)(hT + (size_t)b * H_);
  float acc = b_head[n];
#pragma unroll
  for (int q = 0; q < H_ / 4; ++q) {
    const float4 w = w4[q];
    const float4 h = h4[q];
    acc += w.x * h.x + w.y * h.y + w.z * h.z + w.w * h.w;
  }
  out[o] = acc;
}

// ---------------------------------------------------------------------------
extern "C" void kernel_launch(void* const* d_in, const int* in_sizes, int n_in,
                              void* d_out, int out_size, void* d_ws, size_t ws_size,
                              hipStream_t stream) {
  const float* x        = (const float*)d_in[0];
  const int*   ei       = (const int*)  d_in[1];
  const float* w_lin    = (const float*)d_in[2];
  const float* att_src  = (const float*)d_in[3];
  const float* att_dst  = (const float*)d_in[4];
  const float* gat_bias = (const float*)d_in[5];
  const float* W_ih     = (const float*)d_in[6];
  const float* W_hh     = (const float*)d_in[7];
  const float* b_ih     = (const float*)d_in[8];
  const float* b_hh     = (const float*)d_in[9];
  const float* W_head   = (const float*)d_in[10];
  const float* b_head   = (const float*)d_in[11];
  float* out = (float*)d_out;

  char* ws = (char*)d_ws;
  float* agg_T     = (float*)(ws + 0);              // 2,048,000
  float* pre_gates = (float*)(ws + 2048000);        //   262,144
  float* hT        = (float*)(ws + 2310144);        //     2,048
  float* xT        = (float*)(ws + 2312192);        // 2,048,000
  int*   deg       = (int*)  (ws + 4360192);        //     8,192
  int*   rowptr    = (int*)  (ws + 4368384);        //     8,192
  int*   cursor    = (int*)  (ws + 4376576);        //     8,192
  int*   csr_src   = (int*)  (ws + 4384768);        //   256,000
  float* partial   = (float*)(ws + 4640768);        // 32,768,000 (optional)
  const size_t need = 4640768 + (size_t)KC_ * 65536 * sizeof(float);
  const int use_atomic = (ws_size < need) ? 1 : 0;

  // --- GAT: CSR build + transpose + gather ---
  hipMemsetAsync(deg, 0, N_ * sizeof(int), stream);
  hist_kernel<<<dim3((E_ + 255) / 256), dim3(256), 0, stream>>>(ei, deg);
  scan_kernel<<<dim3(1), dim3(256), 0, stream>>>(deg, rowptr, cursor);
  scatter_kernel<<<dim3((E_ + 255) / 256), dim3(256), 0, stream>>>(ei, cursor, csr_src);
  transpose_kernel<<<dim3((N_ + 31) / 32, BT_ / 32), dim3(256), 0, stream>>>(x, xT);
  gat_gather_kernel<<<dim3(N_), dim3(256), 0, stream>>>(
      xT, rowptr, csr_src, w_lin, att_src, att_dst, agg_T);

  // --- gate matmul ---
  if (use_atomic) {
    hipMemsetAsync(pre_gates, 0, G4_ * BT_ * sizeof(float), stream);
  }
  gate_mfma_kernel<<<dim3(4, KC_), dim3(256), 0, stream>>>(
      W_ih, agg_T, w_lin, gat_bias, partial, pre_gates, use_atomic);
  if (!use_atomic) {
    reduce_kernel<<<dim3(256), dim3(256), 0, stream>>>(partial, pre_gates);
  }

  // --- LSTM + head ---
  lstm_kernel<<<dim3(B_), dim3(256), 0, stream>>>(pre_gates, W_hh, b_ih, b_hh, hT);
  head_kernel<<<dim3((B_ * N_ + 255) / 256), dim3(256), 0, stream>>>(hT, W_head, b_head, out);
}